// Round 16
// baseline (188.175 us; speedup 1.0000x reference)
//
#include <hip/hip_runtime.h>

#define HW 256
#define HWMASK 255
#define CH 128
#define BATCH 8
#define NK 4
#define TSY 16
#define QR 66                    // float4 quads per row: cols -4..259 wrapped
#define RING 38                  // ring rows = 22 live + 16 staged (39.2 KB)
#define NT 8                     // tiles per block (128 rows = half plane)

typedef float f32x4 __attribute__((ext_vector_type(4)));

// ---------------- Kernel A1: partial sums of guidance ----------------
__global__ __launch_bounds__(256) void mean1_kernel(const float* __restrict__ guid,
                                                    float* __restrict__ partial) {
    int blk = blockIdx.x;
    const float4* p = (const float4*)(guid + (size_t)blk * 16384);
    float s = 0.f;
    for (int i = threadIdx.x; i < 4096; i += 256) {
        float4 v = p[i];
        s += (v.x + v.y) + (v.z + v.w);
    }
    for (int off = 32; off; off >>= 1) s += __shfl_down(s, off, 64);
    __shared__ float red[4];
    if ((threadIdx.x & 63) == 0) red[threadIdx.x >> 6] = s;
    __syncthreads();
    if (threadIdx.x == 0) partial[blk] = (red[0] + red[1]) + (red[2] + red[3]);
}

// ---------------- Kernel B: finalize means + MLP + softmax ----------------
__global__ __launch_bounds__(256) void mlp_kernel(const float* __restrict__ partial,
                                                  const float* __restrict__ w1,
                                                  const float* __restrict__ b1,
                                                  const float* __restrict__ w2,
                                                  const float* __restrict__ b2,
                                                  float* __restrict__ wt) {
    __shared__ float gs[BATCH * CH];
    __shared__ float h1[BATCH * 32];
    __shared__ float lg[BATCH * NK];
    int t = threadIdx.x;
    for (int i = t; i < BATCH * CH; i += 256) {
        float4 v = *(const float4*)(partial + i * 4);
        gs[i] = ((v.x + v.y) + (v.z + v.w)) * (1.0f / 65536.0f);
    }
    __syncthreads();
    {
        int b = t >> 5, j = t & 31;
        float acc = b1[j];
        #pragma unroll 4
        for (int c = 0; c < CH; ++c) acc += gs[b * CH + c] * w1[j * CH + c];
        h1[b * 32 + j] = fmaxf(acc, 0.f);
    }
    __syncthreads();
    if (t < BATCH * NK) {
        int b = t >> 2, k = t & 3;
        float acc = b2[k];
        #pragma unroll
        for (int j = 0; j < 32; ++j) acc += h1[b * 32 + j] * w2[k * 32 + j];
        lg[b * NK + k] = acc;
    }
    __syncthreads();
    if (t < BATCH) {
        int b = t;
        float m = lg[b * 4];
        for (int k = 1; k < 4; ++k) m = fmaxf(m, lg[b * 4 + k]);
        float e[4], s = 0.f;
        for (int k = 0; k < 4; ++k) { e[k] = expf(lg[b * 4 + k] - m); s += e[k]; }
        float inv = 1.0f / s;
        for (int k = 0; k < 4; ++k) wt[b * 4 + k] = e[k] * inv;
    }
}

// ---------------- Kernel C: dyn = blend of basis filters, stored FLIPPED ----------------
__global__ __launch_bounds__(256) void dyn_kernel(const float* __restrict__ wt,
                                                  const float* __restrict__ basis,
                                                  float* __restrict__ dynF) {
    int idx = blockIdx.x * 256 + threadIdx.x;
    if (idx >= BATCH * CH * 49) return;
    int ij = idx % 49;
    int bc = idx / 49;
    int c = bc % CH;
    int b = bc / CH;
    float acc = 0.f;
    #pragma unroll
    for (int k = 0; k < NK; ++k)
        acc += wt[b * NK + k] * basis[(k * CH + c) * 49 + ij];
    dynF[bc * 49 + (48 - ij)] = acc;
}

// ---------------- Kernel D: circular depthwise 7x7 conv ----------------
// Ring-buffer LDS (38 rows, 39.2 KB -> 4 blocks/CU) + T14 reg-staging:
// per round stage only the 16 NEW rows (halo re-read eliminated) via
// global->reg loads issued at loop top, ds_write burst + one barrier.
__global__ __launch_bounds__(256) void conv_kernel(const float* __restrict__ x,
                                                   const float* __restrict__ dynF,
                                                   float* __restrict__ out) {
    int bc = blockIdx.x;                  // 0..1023
    int ybase = blockIdx.y * (NT * TSY);  // 0 or 128
    __shared__ float4 ring[RING * QR];    // 40128 B
    const float* xp = x + (size_t)bc * (HW * HW);
    float* op = out + (size_t)bc * (HW * HW);
    int tid = threadIdx.x;

    // filter taps: block-uniform address -> scalar loads into SGPRs
    const float* df = dynF + bc * 49;
    float d[49];
    #pragma unroll
    for (int i = 0; i < 49; ++i) d[i] = df[i];

    // prologue: stage window(0) = rows ybase-3 .. ybase+18 (22 rows = 1452 quads)
    {
        int s0 = (ybase - 3 + RING * 8) % RING;
        const int PE[6] = {0, 256, 512, 768, 1024, 1196};   // last overlaps: dup-safe
        #pragma unroll
        for (int k = 0; k < 6; ++k) {
            int e = PE[k] + tid;
            int ro = e / QR, q = e - ro * QR;
            int gy = (ybase - 3 + ro) & HWMASK;
            int gx = (4 * q - 4) & HWMASK;
            int s = s0 + ro; if (s >= RING) s -= RING;
            ring[s * QR + q] = *(const float4*)(xp + gy * HW + gx);
        }
    }
    __syncthreads();

    // per-thread staging geometry for the 16-row round (1056 quads, 5 chunks)
    int r0, r1, r2, r3, r4;      // row offset within staged range
    int q0, q1, q2, q3, q4;      // quad index within row
    int x0, x1, x2, x3, x4;      // wrapped global col
    {
        int e;
        e = tid;       r0 = e / QR; q0 = e - r0 * QR; x0 = (4 * q0 - 4) & HWMASK;
        e = 256 + tid; r1 = e / QR; q1 = e - r1 * QR; x1 = (4 * q1 - 4) & HWMASK;
        e = 512 + tid; r2 = e / QR; q2 = e - r2 * QR; x2 = (4 * q2 - 4) & HWMASK;
        e = 768 + tid; r3 = e / QR; q3 = e - r3 * QR; x3 = (4 * q3 - 4) & HWMASK;
        e = 800 + tid; r4 = e / QR; q4 = e - r4 * QR; x4 = (4 * q4 - 4) & HWMASK;  // overlaps chunk 3: dup-safe
    }

    int tx = tid & 63, ty = tid >> 6;
    int ly0 = 4 * ty;
    int sb  = (ybase - 3 + RING * 8) % RING;      // ring slot of window start
    int rbm = (ybase + 19) % RING;                // ring slot of first staged row

    float4 pf0, pf1, pf2, pf3, pf4;

    #pragma unroll 1
    for (int t = 0; t < NT; ++t) {
        // issue next 16 rows' global loads into registers (land during compute)
        if (t + 1 < NT) {
            int rb = ybase + 16 * t + 19;
            int gy;
            gy = (rb + r0) & HWMASK; pf0 = *(const float4*)(xp + gy * HW + x0);
            gy = (rb + r1) & HWMASK; pf1 = *(const float4*)(xp + gy * HW + x1);
            gy = (rb + r2) & HWMASK; pf2 = *(const float4*)(xp + gy * HW + x2);
            gy = (rb + r3) & HWMASK; pf3 = *(const float4*)(xp + gy * HW + x3);
            gy = (rb + r4) & HWMASK; pf4 = *(const float4*)(xp + gy * HW + x4);
        }

        // compute tile t from ring window [slots sb .. sb+21 mod RING]
        int y0 = ybase + 16 * t + ly0;
        float acc[4][4] = {};
        #pragma unroll
        for (int rr = 0; rr < 10; ++rr) {
            int s = sb + ly0 + rr; if (s >= RING) s -= RING;
            const float4* rp = &ring[s * QR + tx];
            float4 A = rp[0], B = rp[1], C = rp[2];
            float v[12] = {A.x, A.y, A.z, A.w, B.x, B.y, B.z, B.w, C.x, C.y, C.z, C.w};
            #pragma unroll
            for (int rq = 0; rq < 4; ++rq) {
                int ii = rr - rq;
                if (ii >= 0 && ii <= 6) {
                    #pragma unroll
                    for (int q = 0; q < 4; ++q) {
                        #pragma unroll
                        for (int jj = 0; jj < 7; ++jj)
                            acc[rq][q] += d[ii * 7 + jj] * v[q + jj + 1];
                    }
                }
            }
        }
        #pragma unroll
        for (int rq = 0; rq < 4; ++rq) {
            f32x4 o = {acc[rq][0], acc[rq][1], acc[rq][2], acc[rq][3]};
            __builtin_nontemporal_store(o, (f32x4*)(op + (y0 + rq) * HW + 4 * tx));
        }

        // commit staged rows into ring (slots disjoint from window(t)); 1 barrier
        if (t + 1 < NT) {
            int s;
            s = rbm + r0; if (s >= RING) s -= RING; ring[s * QR + q0] = pf0;
            s = rbm + r1; if (s >= RING) s -= RING; ring[s * QR + q1] = pf1;
            s = rbm + r2; if (s >= RING) s -= RING; ring[s * QR + q2] = pf2;
            s = rbm + r3; if (s >= RING) s -= RING; ring[s * QR + q3] = pf3;
            s = rbm + r4; if (s >= RING) s -= RING; ring[s * QR + q4] = pf4;
            asm volatile("s_waitcnt lgkmcnt(0)" ::: "memory");
            __builtin_amdgcn_s_barrier();
        }
        sb += 16;  if (sb  >= RING) sb  -= RING;
        rbm += 16; if (rbm >= RING) rbm -= RING;
    }
}

extern "C" void kernel_launch(void* const* d_in, const int* in_sizes, int n_in,
                              void* d_out, int out_size, void* d_ws, size_t ws_size,
                              hipStream_t stream) {
    const float* x        = (const float*)d_in[0];
    const float* guidance = (const float*)d_in[1];
    const float* basis    = (const float*)d_in[2];
    const float* w1       = (const float*)d_in[3];
    const float* b1       = (const float*)d_in[4];
    const float* w2       = (const float*)d_in[5];
    const float* b2       = (const float*)d_in[6];
    float* out = (float*)d_out;
    float* ws  = (float*)d_ws;

    float* partial = ws;                  // 4096
    float* wt      = ws + 4096;           // 32
    float* dynF    = ws + 4096 + 32;      // 50176

    mean1_kernel<<<4096, 256, 0, stream>>>(guidance, partial);
    mlp_kernel<<<1, 256, 0, stream>>>(partial, w1, b1, w2, b2, wt);
    dyn_kernel<<<(BATCH * CH * 49 + 255) / 256, 256, 0, stream>>>(wt, basis, dynF);
    conv_kernel<<<dim3(BATCH * CH, HW / (NT * TSY)), 256, 0, stream>>>(x, dynF, out);
}

// Round 17
// 170.993 us; speedup vs baseline: 1.1005x; 1.1005x over previous
//
#include <hip/hip_runtime.h>

#define HW 256
#define HWMASK 255
#define CH 128
#define BATCH 8
#define NK 4
#define STRIP 16           // output rows per wave-strip
#define NIN (STRIP + 6)    // input rows per strip

typedef float f32x4 __attribute__((ext_vector_type(4)));

// ---------------- Kernel A1: partial sums of guidance ----------------
__global__ __launch_bounds__(256) void mean1_kernel(const float* __restrict__ guid,
                                                    float* __restrict__ partial) {
    int blk = blockIdx.x;
    const float4* p = (const float4*)(guid + (size_t)blk * 16384);
    float s = 0.f;
    for (int i = threadIdx.x; i < 4096; i += 256) {
        float4 v = p[i];
        s += (v.x + v.y) + (v.z + v.w);
    }
    for (int off = 32; off; off >>= 1) s += __shfl_down(s, off, 64);
    __shared__ float red[4];
    if ((threadIdx.x & 63) == 0) red[threadIdx.x >> 6] = s;
    __syncthreads();
    if (threadIdx.x == 0) partial[blk] = (red[0] + red[1]) + (red[2] + red[3]);
}

// ---------------- Kernel B: finalize means + MLP + softmax ----------------
__global__ __launch_bounds__(256) void mlp_kernel(const float* __restrict__ partial,
                                                  const float* __restrict__ w1,
                                                  const float* __restrict__ b1,
                                                  const float* __restrict__ w2,
                                                  const float* __restrict__ b2,
                                                  float* __restrict__ wt) {
    __shared__ float gs[BATCH * CH];
    __shared__ float h1[BATCH * 32];
    __shared__ float lg[BATCH * NK];
    int t = threadIdx.x;
    for (int i = t; i < BATCH * CH; i += 256) {
        float4 v = *(const float4*)(partial + i * 4);
        gs[i] = ((v.x + v.y) + (v.z + v.w)) * (1.0f / 65536.0f);
    }
    __syncthreads();
    {
        int b = t >> 5, j = t & 31;
        float acc = b1[j];
        #pragma unroll 4
        for (int c = 0; c < CH; ++c) acc += gs[b * CH + c] * w1[j * CH + c];
        h1[b * 32 + j] = fmaxf(acc, 0.f);
    }
    __syncthreads();
    if (t < BATCH * NK) {
        int b = t >> 2, k = t & 3;
        float acc = b2[k];
        #pragma unroll
        for (int j = 0; j < 32; ++j) acc += h1[b * 32 + j] * w2[k * 32 + j];
        lg[b * NK + k] = acc;
    }
    __syncthreads();
    if (t < BATCH) {
        int b = t;
        float m = lg[b * 4];
        for (int k = 1; k < 4; ++k) m = fmaxf(m, lg[b * 4 + k]);
        float e[4], s = 0.f;
        for (int k = 0; k < 4; ++k) { e[k] = expf(lg[b * 4 + k] - m); s += e[k]; }
        float inv = 1.0f / s;
        for (int k = 0; k < 4; ++k) wt[b * 4 + k] = e[k] * inv;
    }
}

// ---------------- Kernel C: dyn = blend of basis filters, stored FLIPPED ----------------
__global__ __launch_bounds__(256) void dyn_kernel(const float* __restrict__ wt,
                                                  const float* __restrict__ basis,
                                                  float* __restrict__ dynF) {
    int idx = blockIdx.x * 256 + threadIdx.x;
    if (idx >= BATCH * CH * 49) return;
    int ij = idx % 49;
    int bc = idx / 49;
    int c = bc % CH;
    int b = bc / CH;
    float acc = 0.f;
    #pragma unroll
    for (int k = 0; k < NK; ++k)
        acc += wt[b * NK + k] * basis[(k * CH + c) * 49 + ij];
    dynF[bc * 49 + (48 - ij)] = acc;
}

// ---------------- Kernel D: circular depthwise 7x7 conv ----------------
// No LDS data path, no barriers. Wave = 64 lanes x 4 cols = full 256-px row.
// Horizontal halo via cross-lane shuffle of the neighbor quad (circular wrap
// comes free from lane wraparound). Vertical via 7 rolling accumulators.
// Depth-4 row prefetch (pf[i&3], static under full 22-iter unroll).
__global__ __launch_bounds__(256) void conv_kernel(const float* __restrict__ x,
                                                   const float* __restrict__ dynF,
                                                   float* __restrict__ out) {
    int bc = blockIdx.x;                  // 0..1023 plane id
    const float* xp = x + (size_t)bc * (HW * HW);
    float* op = out + (size_t)bc * (HW * HW);
    int tid = threadIdx.x;
    int lane = tid & 63, ty = tid >> 6;
    int yb = blockIdx.y * (4 * STRIP) + ty * STRIP;

    // filter taps: block-uniform address -> scalar loads into SGPRs
    const float* df = dynF + bc * 49;
    float d[49];
    #pragma unroll
    for (int i = 0; i < 49; ++i) d[i] = df[i];

    int col = 4 * lane;                   // own quad: cols 4l..4l+3, 16B aligned
    int lL = (lane + 63) & 63;            // left neighbor lane (circular)
    int lR = (lane + 1) & 63;             // right neighbor lane (circular)

    // prologue: prefetch input rows 0..3 of the window
    float4 pf[4];
    #pragma unroll
    for (int k = 0; k < 4; ++k)
        pf[k] = *(const float4*)(xp + (((yb + k - 3) & HWMASK) * HW) + col);

    float acc[7][4] = {};
    #pragma unroll
    for (int i = 0; i < NIN; ++i) {
        float4 Q = pf[i & 3];
        // reload this slot with row i+4 (lands while rows i..i+3 compute)
        if (i + 4 < NIN)
            pf[i & 3] = *(const float4*)(xp + (((yb + i + 1) & HWMASK) * HW) + col);

        // halo quads from neighbor lanes
        float4 L, R;
        L.x = __shfl(Q.x, lL, 64); L.y = __shfl(Q.y, lL, 64);
        L.z = __shfl(Q.z, lL, 64); L.w = __shfl(Q.w, lL, 64);
        R.x = __shfl(Q.x, lR, 64); R.y = __shfl(Q.y, lR, 64);
        R.z = __shfl(Q.z, lR, 64); R.w = __shfl(Q.w, lR, 64);
        float v[12] = {L.x, L.y, L.z, L.w, Q.x, Q.y, Q.z, Q.w, R.x, R.y, R.z, R.w};

        #pragma unroll
        for (int ii = 0; ii < 7; ++ii) {
            int o = i - ii;                       // output row receiving filter row ii
            if (o >= 0 && o < STRIP) {
                const int s = ((unsigned)o) % 7;  // compile-time under full unroll
                #pragma unroll
                for (int q = 0; q < 4; ++q) {
                    #pragma unroll
                    for (int jj = 0; jj < 7; ++jj)
                        acc[s][q] += d[ii * 7 + jj] * v[q + jj + 1];
                }
            }
        }
        if (i >= 6) {
            const int o = i - 6;
            const int s = ((unsigned)o) % 7;
            f32x4 ov = {acc[s][0], acc[s][1], acc[s][2], acc[s][3]};
            __builtin_nontemporal_store(ov, (f32x4*)(op + (yb + o) * HW + col));
            acc[s][0] = 0.f; acc[s][1] = 0.f; acc[s][2] = 0.f; acc[s][3] = 0.f;
        }
    }
}

extern "C" void kernel_launch(void* const* d_in, const int* in_sizes, int n_in,
                              void* d_out, int out_size, void* d_ws, size_t ws_size,
                              hipStream_t stream) {
    const float* x        = (const float*)d_in[0];
    const float* guidance = (const float*)d_in[1];
    const float* basis    = (const float*)d_in[2];
    const float* w1       = (const float*)d_in[3];
    const float* b1       = (const float*)d_in[4];
    const float* w2       = (const float*)d_in[5];
    const float* b2       = (const float*)d_in[6];
    float* out = (float*)d_out;
    float* ws  = (float*)d_ws;

    float* partial = ws;                  // 4096
    float* wt      = ws + 4096;           // 32
    float* dynF    = ws + 4096 + 32;      // 50176

    mean1_kernel<<<4096, 256, 0, stream>>>(guidance, partial);
    mlp_kernel<<<1, 256, 0, stream>>>(partial, w1, b1, w2, b2, wt);
    dyn_kernel<<<(BATCH * CH * 49 + 255) / 256, 256, 0, stream>>>(wt, basis, dynF);
    conv_kernel<<<dim3(BATCH * CH, HW / (4 * STRIP)), 256, 0, stream>>>(x, dynF, out);
}